// Round 10
// baseline (101.901 us; speedup 1.0000x reference)
//
#include <hip/hip_runtime.h>

// NeRF fused render, R10: interval-scan (R9 algorithm), wave-synchronous and
// barrier-free. One ray per wave (TPR=64): lane == hidden unit h for phase 1,
// lane owns 2 samples for phases 2-3. Difference arrays are wave-private LDS
// regions -> no __syncthreads; phases separated by s_waitcnt lgkmcnt(0) +
// sched_barrier. LDS float adds via __hip_atomic_fetch_add with WAVEFRONT
// scope (native ds_add_f32, no CAS loop).

constexpr int S_TOTAL = 128;
constexpr int BLOCK   = 256;
constexpr int WPB     = BLOCK / 64;    // 4 waves (=rays) per block
constexpr int H       = 64;
constexpr int SLOTS   = 132;           // slots 0..127 used; padded to /4

__global__ __launch_bounds__(BLOCK, 8)
void nerf_scan64(const float* __restrict__ origins,
                 const float* __restrict__ directions,
                 const float* __restrict__ nearp,
                 const float* __restrict__ farp,
                 const float* __restrict__ W1,   // [3][64]
                 const float* __restrict__ b1,   // [64]
                 const float* __restrict__ W2,   // [64][4]
                 const float* __restrict__ b2,   // [4]
                 float* __restrict__ out,        // [B][3]
                 int B)
{
    // per-wave region: channels 0..3 = P-part, 4..7 = Q-part, over 128 slots
    __shared__ float dif[WPB][8][SLOTS];

    const int tid  = threadIdx.x;
    const int wloc = tid >> 6;           // wave (ray) within block
    const int lane = tid & 63;
    const int ray  = blockIdx.x * WPB + wloc;
    const int rayc = (ray < B) ? ray : (B - 1);

    float* const dp = &dif[wloc][0][0];

    // ---- init this wave's region (264 float4) ----
    {
        float4* const dp4 = reinterpret_cast<float4*>(dp);
#pragma unroll
        for (int i = 0; i < 5; ++i) {
            const int idx = lane + 64 * i;
            if (idx < (8 * SLOTS) / 4) dp4[idx] = make_float4(0.f, 0.f, 0.f, 0.f);
        }
    }

    const float nr    = nearp[0];
    const float fr    = farp[0];
    const float delta = (fr - nr) * (1.0f / (float)S_TOTAL);

    const float o0 = origins[rayc * 3 + 0];
    const float o1 = origins[rayc * 3 + 1];
    const float o2 = origins[rayc * 3 + 2];
    float d0 = directions[rayc * 3 + 0];
    float d1 = directions[rayc * 3 + 1];
    float d2 = directions[rayc * 3 + 2];
    const float nrm  = sqrtf(d0 * d0 + d1 * d1 + d2 * d2);
    const float rinv = 1.0f / fmaxf(nrm, 1e-12f);
    d0 *= rinv; d1 *= rinv; d2 *= rinv;

    // fence: init visible before atomics (wave-synchronous)
    asm volatile("s_waitcnt lgkmcnt(0)" ::: "memory");
    __builtin_amdgcn_sched_barrier(0);

    // ---- phase 1: lane h scatters its interval endpoints ----
    {
        const int h = lane;
        const float u0 = W1[0 * H + h];
        const float u1 = W1[1 * H + h];
        const float u2 = W1[2 * H + h];
        const float A  = fmaf(o2, u2, fmaf(o1, u1, fmaf(o0, u0, b1[h])));
        const float Bc = fmaf(d2, u2, fmaf(d1, u1, d0 * u0));
        // g(s) = C0 + s*slope,  m_s = nr + (s+0.5)*delta
        const float C0    = fmaf(nr + 0.5f * delta, Bc, A);
        const float slope = delta * Bc;

        const float4 w2v = *reinterpret_cast<const float4*>(&W2[h * 4]);
        const float wa0 = w2v.x * A,  wa1 = w2v.y * A;
        const float wa2 = w2v.z * A,  wa3 = w2v.w * A;
        const float wb0 = w2v.x * Bc, wb1 = w2v.y * Bc;
        const float wb2 = w2v.z * Bc, wb3 = w2v.w * Bc;

#define ATOM8(IDX, SGN)                                                       \
        {                                                                     \
            const int _i = (IDX);                                             \
            __hip_atomic_fetch_add(dp + 0 * SLOTS + _i, SGN wa0,              \
                __ATOMIC_RELAXED, __HIP_MEMORY_SCOPE_WAVEFRONT);              \
            __hip_atomic_fetch_add(dp + 1 * SLOTS + _i, SGN wa1,              \
                __ATOMIC_RELAXED, __HIP_MEMORY_SCOPE_WAVEFRONT);              \
            __hip_atomic_fetch_add(dp + 2 * SLOTS + _i, SGN wa2,              \
                __ATOMIC_RELAXED, __HIP_MEMORY_SCOPE_WAVEFRONT);              \
            __hip_atomic_fetch_add(dp + 3 * SLOTS + _i, SGN wa3,              \
                __ATOMIC_RELAXED, __HIP_MEMORY_SCOPE_WAVEFRONT);              \
            __hip_atomic_fetch_add(dp + 4 * SLOTS + _i, SGN wb0,              \
                __ATOMIC_RELAXED, __HIP_MEMORY_SCOPE_WAVEFRONT);              \
            __hip_atomic_fetch_add(dp + 5 * SLOTS + _i, SGN wb1,              \
                __ATOMIC_RELAXED, __HIP_MEMORY_SCOPE_WAVEFRONT);              \
            __hip_atomic_fetch_add(dp + 6 * SLOTS + _i, SGN wb2,              \
                __ATOMIC_RELAXED, __HIP_MEMORY_SCOPE_WAVEFRONT);              \
            __hip_atomic_fetch_add(dp + 7 * SLOTS + _i, SGN wb3,              \
                __ATOMIC_RELAXED, __HIP_MEMORY_SCOPE_WAVEFRONT);              \
        }

        if (slope > 0.0f) {                       // active = suffix
            const float sc = -C0 / slope;
            const int lo = (sc < 0.0f) ? 0 : ((int)floorf(sc) + 1);
            if (lo < S_TOTAL) ATOM8(lo, +)
        } else if (slope < 0.0f) {                // active = prefix
            const float sc = -C0 / slope;
            if (sc > 0.0f) {
                ATOM8(0, +)
                const int hi = (int)ceilf(sc);    // exclusive end
                if (hi < S_TOTAL) ATOM8(hi, -)
            }
        } else {
            if (C0 > 0.0f) ATOM8(0, +)
        }
#undef ATOM8
    }

    // fence: scatter visible before scan reads
    asm volatile("s_waitcnt lgkmcnt(0)" ::: "memory");
    __builtin_amdgcn_sched_barrier(0);

    // ---- phase 2: prefix-scan over s (lane owns slots 2*lane, 2*lane+1) ----
    const int s0 = lane * 2;
    float p[8][2];
#pragma unroll
    for (int c = 0; c < 8; ++c) {
        const float2 v = *reinterpret_cast<const float2*>(&dif[wloc][c][s0]);
        p[c][0] = v.x;
        p[c][1] = v.x + v.y;                      // lane-local inclusive
    }
#pragma unroll
    for (int c = 0; c < 8; ++c) {
        float t = p[c][1];
#pragma unroll
        for (int off = 1; off < 64; off <<= 1) {
            const float u = __shfl_up(t, off, 64);
            if (lane >= off) t += u;
        }
        float ex = __shfl_up(t, 1, 64);
        ex = (lane == 0) ? 0.0f : ex;
        p[c][0] += ex;
        p[c][1] += ex;
    }

    // ---- phase 3: evaluate + composite (inclusive cumprod) ----
    const float b20 = b2[0], b21 = b2[1], b22 = b2[2], b23 = b2[3];
    float Tloc = 1.0f, orr = 0.0f, og = 0.0f, ob = 0.0f;
#pragma unroll
    for (int k = 0; k < 2; ++k) {
        const float m  = fmaf((float)(s0 + k) + 0.5f, delta, nr);
        const float c0 = b20 + fmaf(m, p[4][k], p[0][k]);
        const float c1 = b21 + fmaf(m, p[5][k], p[1][k]);
        const float c2 = b22 + fmaf(m, p[6][k], p[2][k]);
        const float sg = b23 + fmaf(m, p[7][k], p[3][k]);
        const float sig = __expf(sg);
        const float e   = __expf(-sig * delta);   // = 1 - alpha
        Tloc *= e;
        const float w = Tloc * (1.0f - e);        // T * alpha (inclusive)
        orr = fmaf(w, __expf(c0), orr);
        og  = fmaf(w, __expf(c1), og);
        ob  = fmaf(w, __expf(c2), ob);
    }

    // ---- stitch across the 64 lanes of this ray ----
    float scan = Tloc;
#pragma unroll
    for (int off = 1; off < 64; off <<= 1) {
        const float v = __shfl_up(scan, off, 64);
        if (lane >= off) scan *= v;
    }
    float pre = __shfl_up(scan, 1, 64);
    if (lane == 0) pre = 1.0f;

    orr *= pre; og *= pre; ob *= pre;
#pragma unroll
    for (int off = 32; off > 0; off >>= 1) {
        orr += __shfl_down(orr, off, 64);
        og  += __shfl_down(og,  off, 64);
        ob  += __shfl_down(ob,  off, 64);
    }

    if (lane == 0 && ray < B) {
        out[ray * 3 + 0] = orr;
        out[ray * 3 + 1] = og;
        out[ray * 3 + 2] = ob;
    }
}

extern "C" void kernel_launch(void* const* d_in, const int* in_sizes, int n_in,
                              void* d_out, int out_size, void* d_ws, size_t ws_size,
                              hipStream_t stream) {
    const float* origins    = (const float*)d_in[0];
    const float* directions = (const float*)d_in[1];
    const float* nearp      = (const float*)d_in[2];
    const float* farp       = (const float*)d_in[3];
    const float* W1         = (const float*)d_in[4];
    const float* b1         = (const float*)d_in[5];
    const float* W2         = (const float*)d_in[6];
    const float* b2         = (const float*)d_in[7];
    float* out              = (float*)d_out;

    const int B    = in_sizes[0] / 3;            // 32768
    const int grid = (B + WPB - 1) / WPB;        // 8192 blocks

    nerf_scan64<<<grid, BLOCK, 0, stream>>>(origins, directions, nearp, farp,
                                            W1, b1, W2, b2, out, B);
}

// Round 11
// 41.526 us; speedup vs baseline: 2.4539x; 2.4539x over previous
//
#include <hip/hip_runtime.h>

// NeRF fused render, R11: masked-affine + intra-chunk correction.
// Exact identity: relu(g_h(m_k)) = mask0_h*g_h(m_k) + c_hk, where mask0_h is
// h's activity at this lane's chunk start and c_hk != 0 only if h's zero
// crossing lies INSIDE this lane's 8-sample chunk (g affine=monotone in m).
//   h-loop (64): P_c += w_c*A*mask0, Q_c += w_c*B*mask0   (~14 VALU)
//   rare branch (crossing in chunk): per-sample corrections (~29/64 taken/wave)
//   per sample: acc_c = b2_c + fma(m, Q_c, P_c) + corr_c[k]; composite as R4.
// Staging/composite/stitch reused from verified R4/R6.

typedef float v2f __attribute__((ext_vector_type(2)));

constexpr int S_TOTAL = 128;
constexpr int TPR     = 16;            // lanes per ray
constexpr int SPT     = S_TOTAL / TPR; // 8 samples per lane
constexpr int BLOCK   = 256;
constexpr int RPB     = BLOCK / TPR;   // 16 rays per block
constexpr int H       = 64;

__global__ __launch_bounds__(BLOCK, 4)
void nerf_ival(const float* __restrict__ origins,
               const float* __restrict__ directions,
               const float* __restrict__ nearp,
               const float* __restrict__ farp,
               const float* __restrict__ W1,   // [3][64]
               const float* __restrict__ b1,   // [64]
               const float* __restrict__ W2,   // [64][4]
               const float* __restrict__ b2,   // [4]
               float* __restrict__ out,        // [B][3]
               int B)
{
    // ABs2[r][h] = {A,B}; ray stride 520B -> per-wave 4 bcast addrs distinct banks
    __shared__ v2f ABs2[RPB][H + 1];
    __shared__ v2f W2p[H][2];            // {w0,w1}, {w2,w3}
    __shared__ float b2s[4];

    const int tid  = threadIdx.x;
    const int ray0 = blockIdx.x * RPB;

    if (tid < H) {
        W2p[tid][0] = (v2f){W2[tid * 4 + 0], W2[tid * 4 + 1]};
        W2p[tid][1] = (v2f){W2[tid * 4 + 2], W2[tid * 4 + 3]};
    }
    if (tid < 4) b2s[tid] = b2[tid];

#pragma unroll
    for (int idx = tid; idx < RPB * H; idx += BLOCK) {
        const int r   = idx >> 6;        // / H
        const int h   = idx & (H - 1);
        const int ray = ray0 + r;
        const float o0 = origins[ray * 3 + 0];
        const float o1 = origins[ray * 3 + 1];
        const float o2 = origins[ray * 3 + 2];
        float d0 = directions[ray * 3 + 0];
        float d1 = directions[ray * 3 + 1];
        float d2 = directions[ray * 3 + 2];
        const float nrm  = sqrtf(d0 * d0 + d1 * d1 + d2 * d2);
        const float rinv = 1.0f / fmaxf(nrm, 1e-12f);
        d0 *= rinv; d1 *= rinv; d2 *= rinv;
        const float u0 = W1[0 * H + h];
        const float u1 = W1[1 * H + h];
        const float u2 = W1[2 * H + h];
        const float A  = fmaf(o2, u2, fmaf(o1, u1, fmaf(o0, u0, b1[h])));
        const float Bc = fmaf(d2, u2, fmaf(d1, u1, d0 * u0));
        ABs2[r][h] = (v2f){A, Bc};
    }
    __syncthreads();

    const int sub  = tid & (TPR - 1);    // lane within ray group
    const int rloc = tid >> 4;           // local ray index
    const int ray  = ray0 + rloc;

    const float nr    = nearp[0];
    const float fr    = farp[0];
    const float delta = (fr - nr) * (1.0f / (float)S_TOTAL);

    // this lane's 8 sample midpoints
    float m[SPT];
    m[0] = fmaf((float)(sub * SPT) + 0.5f, delta, nr);
#pragma unroll
    for (int k = 1; k < SPT; ++k) m[k] = m[k - 1] + delta;
    const float m0 = m[0], m7 = m[SPT - 1];

    // corrections per (channel, sample), seeded with b2
    float acc[4][SPT];
#pragma unroll
    for (int k = 0; k < SPT; ++k) {
        acc[0][k] = b2s[0]; acc[1][k] = b2s[1];
        acc[2][k] = b2s[2]; acc[3][k] = b2s[3];
    }

    float P0 = 0.f, P1 = 0.f, P2 = 0.f, P3 = 0.f;
    float Q0 = 0.f, Q1 = 0.f, Q2 = 0.f, Q3 = 0.f;

#pragma unroll 4
    for (int h = 0; h < H; ++h) {
        const v2f ab  = ABs2[rloc][h];   // {A,B} broadcast per 16-lane group
        const v2f w01 = W2p[h][0];
        const v2f w23 = W2p[h][1];
        const float g0 = fmaf(m0, ab.y, ab.x);
        const float g7 = fmaf(m7, ab.y, ab.x);
        const bool act0 = g0 > 0.0f;
        const bool act7 = g7 > 0.0f;
        const float Am = act0 ? ab.x : 0.0f;
        const float Bm = act0 ? ab.y : 0.0f;
        P0 = fmaf(w01.x, Am, P0); P1 = fmaf(w01.y, Am, P1);
        P2 = fmaf(w23.x, Am, P2); P3 = fmaf(w23.y, Am, P3);
        Q0 = fmaf(w01.x, Bm, Q0); Q1 = fmaf(w01.y, Bm, Q1);
        Q2 = fmaf(w23.x, Bm, Q2); Q3 = fmaf(w23.y, Bm, Q3);
        if (act0 != act7) {              // crossing inside this lane's chunk
#pragma unroll
            for (int k = 0; k < SPT; ++k) {
                const float gk  = fmaf(m[k], ab.y, ab.x);
                const float sel = act0 ? gk : 0.0f;
                const float ck  = fmaxf(gk, 0.0f) - sel;  // relu(g)-mask0*g
                acc[0][k] = fmaf(ck, w01.x, acc[0][k]);
                acc[1][k] = fmaf(ck, w01.y, acc[1][k]);
                acc[2][k] = fmaf(ck, w23.x, acc[2][k]);
                acc[3][k] = fmaf(ck, w23.y, acc[3][k]);
            }
        }
    }

    // local (in-order) composite over this lane's 8 samples (verified R4 form)
    float Tloc = 1.0f, orr = 0.0f, og = 0.0f, ob = 0.0f;
#pragma unroll
    for (int k = 0; k < SPT; ++k) {
        const float c0 = fmaf(m[k], Q0, P0) + acc[0][k];
        const float c1 = fmaf(m[k], Q1, P1) + acc[1][k];
        const float c2 = fmaf(m[k], Q2, P2) + acc[2][k];
        const float sg = fmaf(m[k], Q3, P3) + acc[3][k];
        const float sig = __expf(sg);
        const float e   = __expf(-sig * delta);  // = 1 - alpha
        Tloc *= e;                               // inclusive cumprod
        const float w = Tloc * (1.0f - e);       // T * alpha
        orr = fmaf(w, __expf(c0), orr);
        og  = fmaf(w, __expf(c1), og);
        ob  = fmaf(w, __expf(c2), ob);
    }

    // stitch across the 16 lanes of this ray (verified R4 form)
    float scan = Tloc;
#pragma unroll
    for (int off = 1; off < TPR; off <<= 1) {
        const float v = __shfl_up(scan, off, TPR);
        if (sub >= off) scan *= v;
    }
    float pre = __shfl_up(scan, 1, TPR);
    if (sub == 0) pre = 1.0f;

    orr *= pre; og *= pre; ob *= pre;
#pragma unroll
    for (int off = TPR / 2; off > 0; off >>= 1) {
        orr += __shfl_down(orr, off, TPR);
        og  += __shfl_down(og,  off, TPR);
        ob  += __shfl_down(ob,  off, TPR);
    }

    if (sub == 0) {
        out[ray * 3 + 0] = orr;
        out[ray * 3 + 1] = og;
        out[ray * 3 + 2] = ob;
    }
}

extern "C" void kernel_launch(void* const* d_in, const int* in_sizes, int n_in,
                              void* d_out, int out_size, void* d_ws, size_t ws_size,
                              hipStream_t stream) {
    const float* origins    = (const float*)d_in[0];
    const float* directions = (const float*)d_in[1];
    const float* nearp      = (const float*)d_in[2];
    const float* farp       = (const float*)d_in[3];
    const float* W1         = (const float*)d_in[4];
    const float* b1         = (const float*)d_in[5];
    const float* W2         = (const float*)d_in[6];
    const float* b2         = (const float*)d_in[7];
    float* out              = (float*)d_out;

    const int B     = in_sizes[0] / 3;       // 32768
    const int total = B * TPR;
    const int grid  = (total + BLOCK - 1) / BLOCK;

    nerf_ival<<<grid, BLOCK, 0, stream>>>(origins, directions, nearp, farp,
                                          W1, b1, W2, b2, out, B);
}